// Round 1
// baseline (80.029 us; speedup 1.0000x reference)
//
#include <hip/hip_runtime.h>
#include <hip/hip_bf16.h>
#include <math.h>

typedef __bf16 bf16_t;
typedef __attribute__((ext_vector_type(8))) __bf16 bf16x8;
typedef __attribute__((ext_vector_type(4))) float f32x4;

#define NN 2048
#define CC 256
#define BB 16
#define TWO_PI 6.283185307179586f

__device__ __forceinline__ void gload_lds16(const void* g, void* l) {
    __builtin_amdgcn_global_load_lds(
        (const __attribute__((address_space(1))) void*)g,
        (__attribute__((address_space(3))) void*)l, 16, 0, 0);
}

// ---------------- prologue kernels ----------------

__global__ void build_table(float* __restrict__ table) {
    int m = blockIdx.x * 256 + threadIdx.x;
    table[m] = cosf((float)m * (TWO_PI / (float)NN));
}

// A[k][n] = cos(-2*pi*k*n/N) = table[(k*n) & 2047], bf16, row-major [2048][2048]
__global__ void build_A(bf16_t* __restrict__ A, const float* __restrict__ table) {
    const int k = blockIdx.x;
    const int t = threadIdx.x;
    const int n0 = t * 8;
    unsigned m = ((unsigned)k * (unsigned)n0) & (NN - 1);
    const unsigned step = (unsigned)k & (NN - 1);
    bf16_t vals[8];
#pragma unroll
    for (int j = 0; j < 8; ++j) {
        vals[j] = (bf16_t)table[m];
        m = (m + step) & (NN - 1);
    }
    *reinterpret_cast<uint4*>(A + (size_t)k * NN + n0) =
        *reinterpret_cast<const uint4*>(vals);
}

// x: [B][N][C] f32  ->  xt: [B][C][N] bf16
__global__ void transpose_convert(const float* __restrict__ x, bf16_t* __restrict__ xt) {
    __shared__ float tile[32][33];
    const int b = blockIdx.z;
    const int n0 = blockIdx.x * 32;
    const int c0 = blockIdx.y * 32;
    const int tx = threadIdx.x, ty = threadIdx.y;  // 32 x 8
    const float* xb = x + ((size_t)b * NN + n0) * CC + c0;
#pragma unroll
    for (int i = 0; i < 4; ++i)
        tile[ty + 8 * i][tx] = xb[(size_t)(ty + 8 * i) * CC + tx];
    __syncthreads();
    bf16_t* xtb = xt + ((size_t)b * CC + c0) * NN + n0;
#pragma unroll
    for (int i = 0; i < 4; ++i)
        xtb[(size_t)(ty + 8 * i) * NN + tx] = (bf16_t)tile[tx][ty + 8 * i];
}

// ---------------- main GEMM (m97 structure) ----------------
// out[b](2048x256) = A(2048x2048) * x[b](2048x256)
// Tile: BM=128 (k_out rows), BN=128 (c cols), BK=64. 256 thr = 4 waves (2x2).

#define BM 128
#define BN 128
#define BK 64

__global__ __launch_bounds__(256) void gemm_kernel(const bf16_t* __restrict__ A,
                                                   const bf16_t* __restrict__ Xt,
                                                   float* __restrict__ out) {
    __shared__ bf16_t As[BM * BK];  // [k_out row][n]   16 KB
    __shared__ bf16_t Bs[BN * BK];  // [c row][n]       16 KB

    const int b = blockIdx.y;
    const int tileRow = blockIdx.x >> 1;   // 16 row tiles
    const int tileCol = blockIdx.x & 1;    // 2 col tiles
    const int row0 = tileRow * BM;
    const int col0 = tileCol * BN;

    const int t = threadIdx.x;
    const int lane = t & 63;
    const int wid = t >> 6;
    const int wr = wid >> 1, wc = wid & 1;

    const bf16_t* Ab = A + (size_t)row0 * NN;
    const bf16_t* Bb = Xt + ((size_t)b * CC + col0) * NN;

    f32x4 acc[4][4] = {};

    // staging map: thread t <-> LDS byte offset 16*t (+4096*iter); wave-linear.
    const int srow = t >> 3;            // 0..31
    const int scol = (t & 7) * 8;       // element offset within row

    for (int k0 = 0; k0 < NN; k0 += BK) {
        __syncthreads();
#pragma unroll
        for (int it = 0; it < 4; ++it) {
            const int r = srow + it * 32;
            gload_lds16(Ab + (size_t)r * NN + k0 + scol, As + r * BK + scol);
            gload_lds16(Bb + (size_t)r * NN + k0 + scol, Bs + r * BK + scol);
        }
        __syncthreads();
#pragma unroll
        for (int kk = 0; kk < BK; kk += 32) {
            const int lrow = lane & 15;
            const int koff = kk + (lane >> 4) * 8;
            bf16x8 af[4], bfr[4];
#pragma unroll
            for (int m = 0; m < 4; ++m)
                af[m] = *(const bf16x8*)&As[(wr * 64 + m * 16 + lrow) * BK + koff];
#pragma unroll
            for (int n = 0; n < 4; ++n)
                bfr[n] = *(const bf16x8*)&Bs[(wc * 64 + n * 16 + lrow) * BK + koff];
#pragma unroll
            for (int m = 0; m < 4; ++m)
#pragma unroll
                for (int n = 0; n < 4; ++n)
                    acc[m][n] = __builtin_amdgcn_mfma_f32_16x16x32_bf16(
                        af[m], bfr[n], acc[m][n], 0, 0, 0);
        }
    }

    // epilogue: D col = lane&15, row = (lane>>4)*4 + reg  (m89/m91-verified)
    float* ob = out + ((size_t)b * NN + row0) * CC + col0;
    const int rgrp = lane >> 4;
    const int cl = lane & 15;
#pragma unroll
    for (int m = 0; m < 4; ++m)
#pragma unroll
        for (int n = 0; n < 4; ++n)
#pragma unroll
            for (int r = 0; r < 4; ++r)
                ob[(size_t)(wr * 64 + m * 16 + rgrp * 4 + r) * CC + wc * 64 + n * 16 + cl] =
                    acc[m][n][r];
}

// ---------------- fallback (no/small ws): correct but slow ----------------

__global__ void fallback_kernel(const float* __restrict__ x, float* __restrict__ out) {
    __shared__ float tbl[NN];
    const int b = blockIdx.y;
    const int kbase = blockIdx.x * 16;
    const int t = threadIdx.x;  // 256 = C
    for (int i = t; i < NN; i += 256)
        tbl[i] = cosf((float)i * (TWO_PI / (float)NN));
    __syncthreads();
    float acc[16];
#pragma unroll
    for (int kk = 0; kk < 16; ++kk) acc[kk] = 0.f;
    const float* xb = x + (size_t)b * NN * CC;
    for (int n = 0; n < NN; ++n) {
        const float xv = xb[(size_t)n * CC + t];
#pragma unroll
        for (int kk = 0; kk < 16; ++kk) {
            const int m = (n * (kbase + kk)) & (NN - 1);
            acc[kk] += tbl[m] * xv;
        }
    }
#pragma unroll
    for (int kk = 0; kk < 16; ++kk)
        out[((size_t)b * NN + kbase + kk) * CC + t] = acc[kk];
}

extern "C" void kernel_launch(void* const* d_in, const int* in_sizes, int n_in,
                              void* d_out, int out_size, void* d_ws, size_t ws_size,
                              hipStream_t stream) {
    const float* x = (const float*)d_in[0];
    float* out = (float*)d_out;

    const size_t A_bytes = (size_t)NN * NN * sizeof(bf16_t);            // 8 MB
    const size_t X_bytes = (size_t)BB * CC * NN * sizeof(bf16_t);       // 16 MB
    const size_t T_off = A_bytes + X_bytes;
    const size_t need = T_off + (size_t)NN * sizeof(float);

    if (ws_size >= need) {
        bf16_t* A = (bf16_t*)d_ws;
        bf16_t* Xt = (bf16_t*)((char*)d_ws + A_bytes);
        float* table = (float*)((char*)d_ws + T_off);
        build_table<<<NN / 256, 256, 0, stream>>>(table);
        build_A<<<NN, 256, 0, stream>>>(A, table);
        transpose_convert<<<dim3(NN / 32, CC / 32, BB), dim3(32, 8), 0, stream>>>(x, Xt);
        gemm_kernel<<<dim3((NN / BM) * (CC / BN), BB), 256, 0, stream>>>(A, Xt, out);
    } else {
        fallback_kernel<<<dim3(NN / 16, BB), CC, 0, stream>>>(x, out);
    }
}

// Round 2
// 53.445 us; speedup vs baseline: 1.4974x; 1.4974x over previous
//
#include <hip/hip_runtime.h>
#include <hip/hip_bf16.h>
#include <math.h>

typedef __bf16 bf16_t;
typedef __attribute__((ext_vector_type(8))) __bf16 bf16x8;
typedef __attribute__((ext_vector_type(4))) float f32x4;

#define NN 2048          // original transform length
#define NK 1152          // padded folded length (1025 -> 9*128)
#define CC 256
#define BB 16
#define COLS (BB * CC)   // 4096 flattened (b,c) columns
#define TWO_PI 6.283185307179586f

__device__ __forceinline__ void gload_lds16(const void* g, void* l) {
    __builtin_amdgcn_global_load_lds(
        (const __attribute__((address_space(1))) void*)g,
        (__attribute__((address_space(3))) void*)l, 16, 0, 0);
}

// ---------------- prologue kernels ----------------

__global__ void build_table(float* __restrict__ table) {
    int m = blockIdx.x * 256 + threadIdx.x;
    table[m] = cosf((float)m * (TWO_PI / (float)NN));
}

// A[k][n] = cos(2*pi*k*n/2048), k,n in [0,1152). Row-major stride NK.
// (rows k>1024 are discarded by the epilogue; cols n>1024 multiply zeros)
__global__ void build_A(bf16_t* __restrict__ A, const float* __restrict__ table) {
    const int k = blockIdx.x;
    const int t = threadIdx.x;
    const int n0 = t * 8;
    if (n0 >= NK) return;
    unsigned m = ((unsigned)k * (unsigned)n0) & (NN - 1);
    const unsigned step = (unsigned)k & (NN - 1);
    bf16_t vals[8];
#pragma unroll
    for (int j = 0; j < 8; ++j) {
        vals[j] = (bf16_t)table[m];
        m = (m + step) & (NN - 1);
    }
    *reinterpret_cast<uint4*>(A + (size_t)k * NK + n0) =
        *reinterpret_cast<const uint4*>(vals);
}

// x: [B][2048][C] f32  ->  Yt: [(b,c)][NK] bf16 with even-fold:
//   y[0]=x[0]; y[n]=x[n]+x[2048-n] (1<=n<=1023); y[1024]=x[1024]; y[n>=1025]=0
__global__ void fold_transpose(const float* __restrict__ x, bf16_t* __restrict__ yt) {
    __shared__ float tile[32][33];
    const int b = blockIdx.z;
    const int n0 = blockIdx.x * 32;   // 36 tiles -> n in [0,1152)
    const int c0 = blockIdx.y * 32;
    const int tx = threadIdx.x, ty = threadIdx.y;  // 32 x 8
    const float* xb = x + (size_t)b * NN * CC;
#pragma unroll
    for (int i = 0; i < 4; ++i) {
        const int n = n0 + ty + 8 * i;
        float v = 0.f;
        if (n <= 1024) v = xb[(size_t)n * CC + c0 + tx];
        if (n >= 1 && n <= 1023) v += xb[(size_t)(NN - n) * CC + c0 + tx];
        tile[ty + 8 * i][tx] = v;
    }
    __syncthreads();
    bf16_t* ytb = yt + ((size_t)b * CC + c0) * NK + n0;
#pragma unroll
    for (int i = 0; i < 4; ++i)
        ytb[(size_t)(ty + 8 * i) * NK + tx] = (bf16_t)tile[tx][ty + 8 * i];
}

// ---------------- main GEMM ----------------
// out_rows(k=0..1151) x cols(4096) = A(1152x1152) * Yt^T ; epilogue writes
// out[b,k,c] for k<=1024 and mirror out[b,2048-k,c] for 1<=k<=1023.
// Tile: BM=128, BN=64, BK=64. 256 thr = 4 waves (2x2), wave = 64x32 out.

#define BM 128
#define BN 64
#define BK 64

__global__ __launch_bounds__(256) void gemm_kernel(const bf16_t* __restrict__ A,
                                                   const bf16_t* __restrict__ Yt,
                                                   float* __restrict__ out) {
    __shared__ bf16_t As[BM * BK];  // 16 KB
    __shared__ bf16_t Bs[BN * BK];  // 8 KB

    const int col0 = blockIdx.x * BN;   // 64 col tiles
    const int row0 = blockIdx.y * BM;   // 9 row tiles

    const int t = threadIdx.x;
    const int lane = t & 63;
    const int wid = t >> 6;
    const int wr = wid >> 1, wc = wid & 1;

    const bf16_t* Ab = A + (size_t)row0 * NK;
    const bf16_t* Bb = Yt + (size_t)col0 * NK;

    f32x4 acc[4][2] = {};

    const int srow = t >> 3;            // 0..31
    const int scol = (t & 7) * 8;       // element offset within row

    for (int k0 = 0; k0 < NK; k0 += BK) {
        __syncthreads();
#pragma unroll
        for (int it = 0; it < 4; ++it) {
            const int r = srow + it * 32;
            gload_lds16(Ab + (size_t)r * NK + k0 + scol, As + r * BK + scol);
        }
#pragma unroll
        for (int it = 0; it < 2; ++it) {
            const int r = srow + it * 32;
            gload_lds16(Bb + (size_t)r * NK + k0 + scol, Bs + r * BK + scol);
        }
        __syncthreads();
#pragma unroll
        for (int kk = 0; kk < BK; kk += 32) {
            const int lrow = lane & 15;
            const int koff = kk + (lane >> 4) * 8;
            bf16x8 af[4], bfr[2];
#pragma unroll
            for (int m = 0; m < 4; ++m)
                af[m] = *(const bf16x8*)&As[(wr * 64 + m * 16 + lrow) * BK + koff];
#pragma unroll
            for (int n = 0; n < 2; ++n)
                bfr[n] = *(const bf16x8*)&Bs[(wc * 32 + n * 16 + lrow) * BK + koff];
#pragma unroll
            for (int m = 0; m < 4; ++m)
#pragma unroll
                for (int n = 0; n < 2; ++n)
                    acc[m][n] = __builtin_amdgcn_mfma_f32_16x16x32_bf16(
                        af[m], bfr[n], acc[m][n], 0, 0, 0);
        }
    }

    // epilogue: D col = lane&15, row = (lane>>4)*4 + reg
    const int rgrp = lane >> 4;
    const int cl = lane & 15;
#pragma unroll
    for (int m = 0; m < 4; ++m)
#pragma unroll
        for (int n = 0; n < 2; ++n) {
            const int col = col0 + wc * 32 + n * 16 + cl;
            const int b = col >> 8;
            const int c = col & (CC - 1);
            float* obc = out + ((size_t)b * NN) * CC + c;
#pragma unroll
            for (int r = 0; r < 4; ++r) {
                const int k = row0 + wr * 64 + m * 16 + rgrp * 4 + r;
                const float v = acc[m][n][r];
                if (k <= 1024) obc[(size_t)k * CC] = v;
                if (k >= 1 && k <= 1023) obc[(size_t)(NN - k) * CC] = v;
            }
        }
}

// ---------------- fallback (no/small ws): correct but slow ----------------

__global__ void fallback_kernel(const float* __restrict__ x, float* __restrict__ out) {
    __shared__ float tbl[NN];
    const int b = blockIdx.y;
    const int kbase = blockIdx.x * 16;
    const int t = threadIdx.x;  // 256 = C
    for (int i = t; i < NN; i += 256)
        tbl[i] = cosf((float)i * (TWO_PI / (float)NN));
    __syncthreads();
    float acc[16];
#pragma unroll
    for (int kk = 0; kk < 16; ++kk) acc[kk] = 0.f;
    const float* xb = x + (size_t)b * NN * CC;
    for (int n = 0; n < NN; ++n) {
        const float xv = xb[(size_t)n * CC + t];
#pragma unroll
        for (int kk = 0; kk < 16; ++kk) {
            const int m = (n * (kbase + kk)) & (NN - 1);
            acc[kk] += tbl[m] * xv;
        }
    }
#pragma unroll
    for (int kk = 0; kk < 16; ++kk)
        out[((size_t)b * NN + kbase + kk) * CC + t] = acc[kk];
}

extern "C" void kernel_launch(void* const* d_in, const int* in_sizes, int n_in,
                              void* d_out, int out_size, void* d_ws, size_t ws_size,
                              hipStream_t stream) {
    const float* x = (const float*)d_in[0];
    float* out = (float*)d_out;

    const size_t A_bytes = (size_t)NK * NK * sizeof(bf16_t);        // ~2.65 MB
    const size_t Y_bytes = (size_t)COLS * NK * sizeof(bf16_t);      // ~9.44 MB
    const size_t T_off = A_bytes + Y_bytes;
    const size_t need = T_off + (size_t)NN * sizeof(float);

    if (ws_size >= need) {
        bf16_t* A = (bf16_t*)d_ws;
        bf16_t* Yt = (bf16_t*)((char*)d_ws + A_bytes);
        float* table = (float*)((char*)d_ws + T_off);
        build_table<<<NN / 256, 256, 0, stream>>>(table);
        build_A<<<NK, 256, 0, stream>>>(A, table);
        fold_transpose<<<dim3(NK / 32, CC / 32, BB), dim3(32, 8), 0, stream>>>(x, Yt);
        gemm_kernel<<<dim3(COLS / BN, NK / BM), 256, 0, stream>>>(A, Yt, out);
    } else {
        fallback_kernel<<<dim3(NN / 16, BB), CC, 0, stream>>>(x, out);
    }
}

// Round 3
// 30.655 us; speedup vs baseline: 2.6107x; 1.7435x over previous
//
#include <hip/hip_runtime.h>
#include <hip/hip_bf16.h>
#include <math.h>

typedef __bf16 bf16_t;
typedef __attribute__((ext_vector_type(8))) __bf16 bf16x8;
typedef __attribute__((ext_vector_type(4))) float f32x4;

#define NN 2048
#define CC 256
#define BB 16
#define COLS (BB * CC)     // 4096 flattened (b,c) columns

// Even-k half: out[2j] = sum_m e[m] cos(2*pi*m*j/1024), j=0..512, m=0..512
#define NE_M 640           // padded rows (513 -> 5*128)
#define NE_K 576           // padded K (513 -> 9*64)
// Odd-k half: out[2j+1] = sum_m o[m] cos(2*pi*m*(2j+1)/2048), j,m = 0..511
#define NO_M 512
#define NO_K 512

#define ANG (6.283185307179586f / 2048.0f)   // 2*pi/2048

__device__ __forceinline__ void gload_lds16(const void* g, void* l) {
    __builtin_amdgcn_global_load_lds(
        (const __attribute__((address_space(1))) void*)g,
        (__attribute__((address_space(3))) void*)l, 16, 0, 0);
}

// ---------------- merged prologue ----------------
// blocks [0,180): build AE (640x576)  [j = u/72, m0 = (u%72)*8]
// blocks [180,308): build AO (512x512)
// blocks [308,2612): fold+transpose x -> Et (4096x576), Ot (4096x512)
#define NBLK_AE 180
#define NBLK_AO 128
#define NBLK_FOLD (BB * 18 * 8)

__global__ __launch_bounds__(256) void prep_kernel(const float* __restrict__ x,
                                                   bf16_t* __restrict__ AE,
                                                   bf16_t* __restrict__ AO,
                                                   bf16_t* __restrict__ Et,
                                                   bf16_t* __restrict__ Ot) {
    __shared__ float tE[32][33];
    __shared__ float tO[32][33];
    const int blk = blockIdx.x;
    const int t = threadIdx.x;

    if (blk < NBLK_AE) {                       // AE[j][m] = cos(2pi*(2jm)/2048)
        const int u = blk * 256 + t;
        const int j = u / 72;
        const int m0 = (u - j * 72) * 8;
        const unsigned step = (unsigned)(2 * j) & (NN - 1);
        unsigned idx = ((unsigned)m0 * (unsigned)(2 * j)) & (NN - 1);
        bf16_t vals[8];
#pragma unroll
        for (int q = 0; q < 8; ++q) {
            vals[q] = (bf16_t)cosf((float)idx * ANG);
            idx = (idx + step) & (NN - 1);
        }
        *reinterpret_cast<uint4*>(AE + (size_t)j * NE_K + m0) =
            *reinterpret_cast<const uint4*>(vals);
        return;
    }
    if (blk < NBLK_AE + NBLK_AO) {             // AO[j][m] = cos(2pi*(m(2j+1))/2048)
        const int u = (blk - NBLK_AE) * 256 + t;
        const int j = u >> 6;
        const int m0 = (u & 63) * 8;
        const unsigned step = (unsigned)(2 * j + 1) & (NN - 1);
        unsigned idx = ((unsigned)m0 * (unsigned)(2 * j + 1)) & (NN - 1);
        bf16_t vals[8];
#pragma unroll
        for (int q = 0; q < 8; ++q) {
            vals[q] = (bf16_t)cosf((float)idx * ANG);
            idx = (idx + step) & (NN - 1);
        }
        *reinterpret_cast<uint4*>(AO + (size_t)j * NO_K + m0) =
            *reinterpret_cast<const uint4*>(vals);
        return;
    }

    // ---- fold + transpose ----
    const int f = blk - (NBLK_AE + NBLK_AO);   // b*144 + mtile*8 + ctile
    const int b = f / 144;
    const int rem = f - b * 144;
    const int mtile = rem >> 3;                // 0..17  (m0 = mtile*32, up to 575)
    const int ctile = rem & 7;
    const int m0 = mtile * 32;
    const int c0 = ctile * 32;
    const int tx = t & 31;
    const int tyy = t >> 5;                    // 0..7

    const float* xb = x + (size_t)b * NN * CC;
#pragma unroll
    for (int i = 0; i < 4; ++i) {
        const int m = m0 + tyy + 8 * i;
        const int r2 = 1024 - m;
        const int r3 = 1024 + m;
        const int r4 = (m == 0) ? 0 : (2048 - m);
        const float w23 = (m == 0) ? 0.5f : 1.0f;
        const float w4  = (m == 0) ? 0.0f : 1.0f;
        const float wall = (m == 512) ? 0.5f : ((m > 512) ? 0.0f : 1.0f);
        const float x1 = xb[(size_t)m  * CC + c0 + tx];
        const float x2 = xb[(size_t)r2 * CC + c0 + tx];
        const float x3 = xb[(size_t)r3 * CC + c0 + tx];
        const float x4 = xb[(size_t)r4 * CC + c0 + tx];
        const float s23 = x2 + x3;
        tE[tyy + 8 * i][tx] = wall * (x1 + w23 * s23 + w4 * x4);
        tO[tyy + 8 * i][tx] = x1 - w23 * s23 + w4 * x4;
    }
    __syncthreads();
#pragma unroll
    for (int i = 0; i < 4; ++i) {
        const int cl_ = tyy + 8 * i;
        const size_t rowc = (size_t)b * CC + c0 + cl_;
        Et[rowc * NE_K + m0 + tx] = (bf16_t)tE[tx][cl_];
        if (mtile < 16)
            Ot[rowc * NO_K + m0 + tx] = (bf16_t)tO[tx][cl_];
    }
}

// ---------------- fused dual GEMM ----------------
// blockIdx.y 0..4: even half (AE 640x576 * Et^T), 5..8: odd half (AO 512x512 * Ot^T)
// Tile BM=128, BN=64, BK=64; 256 thr = 4 waves (2x2).

#define BM 128
#define BN 64
#define BK 64

__global__ __launch_bounds__(256) void gemm_kernel(const bf16_t* __restrict__ AE,
                                                   const bf16_t* __restrict__ AO,
                                                   const bf16_t* __restrict__ Et,
                                                   const bf16_t* __restrict__ Ot,
                                                   float* __restrict__ out) {
    __shared__ bf16_t As[BM * BK];  // 16 KB
    __shared__ bf16_t Bs[BN * BK];  // 8 KB

    const int col0 = blockIdx.x * BN;
    const bool isE = blockIdx.y < 5;
    int row0, stride, ksteps;
    const bf16_t *Ab, *Bb;
    if (isE) {
        row0 = blockIdx.y * BM; stride = NE_K; ksteps = NE_K / BK;
        Ab = AE + (size_t)row0 * NE_K;
        Bb = Et + (size_t)col0 * NE_K;
    } else {
        row0 = (blockIdx.y - 5) * BM; stride = NO_K; ksteps = NO_K / BK;
        Ab = AO + (size_t)row0 * NO_K;
        Bb = Ot + (size_t)col0 * NO_K;
    }

    const int t = threadIdx.x;
    const int lane = t & 63;
    const int wid = t >> 6;
    const int wr = wid >> 1, wc = wid & 1;

    f32x4 acc[4][2] = {};

    const int srow = t >> 3;            // 0..31
    const int scol = (t & 7) * 8;

    for (int kt = 0; kt < ksteps; ++kt) {
        const int k0 = kt * BK;
        __syncthreads();
#pragma unroll
        for (int it = 0; it < 4; ++it) {
            const int r = srow + it * 32;
            gload_lds16(Ab + (size_t)r * stride + k0 + scol, As + r * BK + scol);
        }
#pragma unroll
        for (int it = 0; it < 2; ++it) {
            const int r = srow + it * 32;
            gload_lds16(Bb + (size_t)r * stride + k0 + scol, Bs + r * BK + scol);
        }
        __syncthreads();
#pragma unroll
        for (int kk = 0; kk < BK; kk += 32) {
            const int lrow = lane & 15;
            const int koff = kk + (lane >> 4) * 8;
            bf16x8 af[4], bfr[2];
#pragma unroll
            for (int m = 0; m < 4; ++m)
                af[m] = *(const bf16x8*)&As[(wr * 64 + m * 16 + lrow) * BK + koff];
#pragma unroll
            for (int n = 0; n < 2; ++n)
                bfr[n] = *(const bf16x8*)&Bs[(wc * 32 + n * 16 + lrow) * BK + koff];
#pragma unroll
            for (int m = 0; m < 4; ++m)
#pragma unroll
                for (int n = 0; n < 2; ++n)
                    acc[m][n] = __builtin_amdgcn_mfma_f32_16x16x32_bf16(
                        af[m], bfr[n], acc[m][n], 0, 0, 0);
        }
    }

    // epilogue: D col = lane&15, row = (lane>>4)*4 + reg
    const int rgrp = lane >> 4;
    const int cl = lane & 15;
#pragma unroll
    for (int m = 0; m < 4; ++m)
#pragma unroll
        for (int n = 0; n < 2; ++n) {
            const int col = col0 + wc * 32 + n * 16 + cl;
            const int b = col >> 8;
            const int c = col & (CC - 1);
            float* obc = out + (size_t)b * NN * CC + c;
#pragma unroll
            for (int r = 0; r < 4; ++r) {
                const int j = row0 + wr * 64 + m * 16 + rgrp * 4 + r;
                const float v = acc[m][n][r];
                if (isE) {
                    if (j <= 512) obc[(size_t)(2 * j) * CC] = v;
                    if (j >= 1 && j <= 511) obc[(size_t)(2048 - 2 * j) * CC] = v;
                } else {
                    if (j <= 511) {
                        obc[(size_t)(2 * j + 1) * CC] = v;
                        obc[(size_t)(2047 - 2 * j) * CC] = v;
                    }
                }
            }
        }
}

// ---------------- fallback (no/small ws): correct but slow ----------------

__global__ void fallback_kernel(const float* __restrict__ x, float* __restrict__ out) {
    __shared__ float tbl[NN];
    const int b = blockIdx.y;
    const int kbase = blockIdx.x * 16;
    const int t = threadIdx.x;  // 256 = C
    for (int i = t; i < NN; i += 256)
        tbl[i] = cosf((float)i * ANG);
    __syncthreads();
    float acc[16];
#pragma unroll
    for (int kk = 0; kk < 16; ++kk) acc[kk] = 0.f;
    const float* xb = x + (size_t)b * NN * CC;
    for (int n = 0; n < NN; ++n) {
        const float xv = xb[(size_t)n * CC + t];
#pragma unroll
        for (int kk = 0; kk < 16; ++kk) {
            const int m = (n * (kbase + kk)) & (NN - 1);
            acc[kk] += tbl[m] * xv;
        }
    }
#pragma unroll
    for (int kk = 0; kk < 16; ++kk)
        out[((size_t)b * NN + kbase + kk) * CC + t] = acc[kk];
}

extern "C" void kernel_launch(void* const* d_in, const int* in_sizes, int n_in,
                              void* d_out, int out_size, void* d_ws, size_t ws_size,
                              hipStream_t stream) {
    const float* x = (const float*)d_in[0];
    float* out = (float*)d_out;

    const size_t AE_bytes = (size_t)NE_M * NE_K * sizeof(bf16_t);   // 737,280
    const size_t AO_bytes = (size_t)NO_M * NO_K * sizeof(bf16_t);   // 524,288
    const size_t Et_bytes = (size_t)COLS * NE_K * sizeof(bf16_t);   // 4,718,592
    const size_t Ot_bytes = (size_t)COLS * NO_K * sizeof(bf16_t);   // 4,194,304
    const size_t need = AE_bytes + AO_bytes + Et_bytes + Ot_bytes;  // ~9.7 MB

    if (ws_size >= need) {
        bf16_t* AE = (bf16_t*)d_ws;
        bf16_t* AO = (bf16_t*)((char*)d_ws + AE_bytes);
        bf16_t* Et = (bf16_t*)((char*)d_ws + AE_bytes + AO_bytes);
        bf16_t* Ot = (bf16_t*)((char*)d_ws + AE_bytes + AO_bytes + Et_bytes);
        prep_kernel<<<NBLK_AE + NBLK_AO + NBLK_FOLD, 256, 0, stream>>>(x, AE, AO, Et, Ot);
        gemm_kernel<<<dim3(COLS / BN, 9), 256, 0, stream>>>(AE, AO, Et, Ot, out);
    } else {
        fallback_kernel<<<dim3(NN / 16, BB), CC, 0, stream>>>(x, out);
    }
}